// Round 2
// baseline (16670.760 us; speedup 1.0000x reference)
//
#include <hip/hip_runtime.h>
#include <hip/hip_cooperative_groups.h>
#include <cstdint>
#include <cstddef>

namespace cg = cooperative_groups;

typedef __bf16 bf16;
typedef __bf16 bf16x8 __attribute__((ext_vector_type(8)));
typedef float f32x4 __attribute__((ext_vector_type(4)));

#define MFMA16(a, b, c) __builtin_amdgcn_mfma_f32_16x16x32_bf16((a), (b), (c), 0, 0, 0)

__device__ __forceinline__ float fast_tanh(float x) {
  x = fminf(fmaxf(x, -15.f), 15.f);
  float e = __expf(2.f * x);
  return (e - 1.f) / (e + 1.f);
}
__device__ __forceinline__ float fast_sigmoid(float x) {
  return 1.f / (1.f + __expf(-x));
}

// ---------------- setup kernels ----------------

__global__ void cast_split_kernel(const float* __restrict__ src,
                                  bf16* __restrict__ hi, bf16* __restrict__ lo, int n) {
  int i = blockIdx.x * 256 + threadIdx.x;
  if (i < n) {
    float x = src[i];
    bf16 h = (bf16)x;
    hi[i] = h;
    lo[i] = (bf16)(x - (float)h);
  }
}

__global__ void tc_kernel(const float* __restrict__ src, bf16* __restrict__ hi,
                          bf16* __restrict__ lo, int R, int C) {
  __shared__ float tile[32][33];
  int c0 = blockIdx.x * 32, r0 = blockIdx.y * 32;
  int tx = threadIdx.x & 31, ty = threadIdx.x >> 5;
  for (int i = ty; i < 32; i += 8)
    tile[i][tx] = src[(size_t)(r0 + i) * C + c0 + tx];
  __syncthreads();
  for (int i = ty; i < 32; i += 8) {
    float x = tile[tx][i];
    bf16 h = (bf16)x;
    size_t idx = (size_t)(c0 + i) * R + r0 + tx;
    hi[idx] = h;
    if (lo) lo[idx] = (bf16)(x - (float)h);
  }
}

__device__ __forceinline__ void gemm_split_body(const bf16* __restrict__ Ahi,
                                                const bf16* __restrict__ Alo, int lda,
                                                const bf16* __restrict__ Bhi,
                                                const bf16* __restrict__ Blo, int ldb,
                                                float* __restrict__ C, int ldc,
                                                int mb, int nb, int kSteps) {
  int lane = threadIdx.x & 63, wave = threadIdx.x >> 6;
  int mrow = mb * 64 + wave * 16 + (lane & 15);
  int qk = (lane >> 4) * 8;
  const bf16* ah = Ahi + (size_t)mrow * lda + qk;
  const bf16* al = Alo + (size_t)mrow * lda + qk;
  int ncol = nb * 64 + (lane & 15);
  const bf16* bh[4]; const bf16* bl[4];
#pragma unroll
  for (int j = 0; j < 4; ++j) {
    bh[j] = Bhi + (size_t)(ncol + 16 * j) * ldb + qk;
    bl[j] = Blo + (size_t)(ncol + 16 * j) * ldb + qk;
  }
  f32x4 acc[4];
#pragma unroll
  for (int j = 0; j < 4; ++j) acc[j] = {0.f, 0.f, 0.f, 0.f};
#pragma unroll 2
  for (int s = 0; s < kSteps; ++s) {
    bf16x8 Ah = *(const bf16x8*)ah; ah += 32;
    bf16x8 Al = *(const bf16x8*)al; al += 32;
#pragma unroll
    for (int j = 0; j < 4; ++j) {
      bf16x8 Bh = *(const bf16x8*)bh[j]; bh[j] += 32;
      bf16x8 Bl = *(const bf16x8*)bl[j]; bl[j] += 32;
      acc[j] = MFMA16(Ah, Bh, acc[j]);
      acc[j] = MFMA16(Ah, Bl, acc[j]);
      acc[j] = MFMA16(Al, Bh, acc[j]);
    }
  }
  int row = mb * 64 + wave * 16 + (lane >> 4) * 4;
  int col = nb * 64 + (lane & 15);
#pragma unroll
  for (int j = 0; j < 4; ++j)
#pragma unroll
    for (int i = 0; i < 4; ++i)
      C[(size_t)(row + i) * ldc + col + j * 16] = acc[j][i];
}

__global__ __launch_bounds__(256) void gemm_split_kernel(const bf16* __restrict__ Ahi,
                                                         const bf16* __restrict__ Alo, int lda,
                                                         const bf16* __restrict__ Bhi,
                                                         const bf16* __restrict__ Blo, int ldb,
                                                         float* __restrict__ C, int ldc,
                                                         int nbN, int kSteps) {
  gemm_split_body(Ahi, Alo, lda, Bhi, Blo, ldb, C, ldc, blockIdx.x / nbN, blockIdx.x % nbN, kSteps);
}

// ---------------- persistent cooperative kernel ----------------

struct MegaArgs {
  const float* U_h; const float* attnb; const float* vvec; const float* inseq;
  float* Ws;
  bf16* ctx_hi; bf16* ctx_lo;
  bf16* Ebf; const bf16* EyT; float* t1f;
  float* Ef; float* Zpart; float* invZ; float* out;
  float* sbuf0; float* sbuf1; bf16* shi0; bf16* slo0; bf16* shi1; bf16* slo1;
  const bf16* Wih_hi; const bf16* Wih_lo; const bf16* Whh_hi; const bf16* Whh_lo;
  const float* b_ih; const float* b_hh;
  const bf16* UoT_hi; const bf16* UoT_lo; const bf16* VoT_hi; const bf16* VoT_lo;
  const bf16* CoT_hi; const bf16* CoT_lo; const bf16* WT_hi; const bf16* WT_lo;
  const bf16* WoT; bf16* tm_bf;
};

__global__ __launch_bounds__(512) void mega_kernel(MegaArgs a) {
  cg::grid_group grid = cg::this_grid();
  __shared__ __align__(16) float smem[6400];  // 25.6 KB union
  int bx = blockIdx.x, tid = threadIdx.x;
  int lane = tid & 63, wave = tid >> 6;
  int half = tid >> 8, vt = tid & 255;

  for (int t = 0; t < 64; ++t) {
    const float* s_cur = (t & 1) ? a.sbuf1 : a.sbuf0;
    float* s_nxt = (t & 1) ? a.sbuf0 : a.sbuf1;
    const bf16* shc = (t & 1) ? a.shi1 : a.shi0;
    const bf16* slc = (t & 1) ? a.slo1 : a.slo0;
    bf16* shn = (t & 1) ? a.shi0 : a.shi1;
    bf16* sln = (t & 1) ? a.slo0 : a.slo1;

    // ======== Phase A: attention + invZ/out(t-1)  |  t1 += E @ EyT ========
    if (bx < 32) {
      int b = bx * 2 + half;
      float* sWs = smem;               // [2][512]
      float* sV = smem + 1024;         // [2][512]
      float* sE = smem + 2048;         // [2][64]
      float* sAl = smem + 2176;        // [2][64]
      float* w4 = smem + 2304;         // [2][4]
      float part0 = 0.f;
      if (t > 0)
        for (int nb = vt; nb < 500; nb += 256) part0 += a.Zpart[nb * 64 + b];
#pragma unroll
      for (int off = 32; off; off >>= 1) part0 += __shfl_xor(part0, off);
      if ((vt & 63) == 0) w4[half * 4 + (vt >> 6)] = part0;
      for (int c = vt; c < 512; c += 256) {
        sWs[half * 512 + c] = a.Ws[b * 512 + c] + a.attnb[c];
        sV[half * 512 + c] = a.vvec[c];
      }
      __syncthreads();
      float iz = (t == 0) ? 0.f
                          : 1.f / (w4[half * 4] + w4[half * 4 + 1] + w4[half * 4 + 2] + w4[half * 4 + 3]);
      if (vt == 0) a.invZ[b] = iz;
      int j = vt >> 2, q = vt & 3;
      const float* uh = a.U_h + ((size_t)(b * 64 + j)) * 512 + q * 128;
      const float* Wsb = sWs + half * 512;
      const float* Vb = sV + half * 512;
      float part = 0.f;
#pragma unroll 4
      for (int c = 0; c < 128; ++c) {
        int cc = q * 128 + c;
        part += Vb[cc] * fast_tanh(Wsb[cc] + uh[c]);
      }
      part += __shfl_xor(part, 1);
      part += __shfl_xor(part, 2);
      if (q == 0) sE[half * 64 + j] = part;
      __syncthreads();
      if (vt < 64) {
        float x = sE[half * 64 + vt];
        float m = x;
        for (int off = 32; off; off >>= 1) m = fmaxf(m, __shfl_xor(m, off));
        float aa = __expf(x - m);
        float ss = aa;
        for (int off = 32; off; off >>= 1) ss += __shfl_xor(ss, off);
        sAl[half * 64 + vt] = aa / ss;
      }
      __syncthreads();
      for (int c = vt; c < 512; c += 256) {
        float acc = 0.f;
        const float* ip = a.inseq + ((size_t)b * 64) * 512 + c;
#pragma unroll 8
        for (int jj = 0; jj < 64; ++jj) acc += sAl[half * 64 + jj] * ip[(size_t)jj * 512];
        bf16 hh = (bf16)acc;
        a.ctx_hi[b * 512 + c] = hh;
        a.ctx_lo[b * 512 + c] = (bf16)(acc - (float)hh);
      }
      if (t > 0) {
        const f32x4* er = (const f32x4*)(a.Ef + (size_t)b * 32000);
        f32x4* orow = (f32x4*)(a.out + ((size_t)(t - 1) * 64 + b) * 32000);
        for (int v = vt; v < 8000; v += 256) {
          f32x4 e = er[v];
          f32x4 o = {e[0] * iz, e[1] * iz, e[2] * iz, e[3] * iz};
          orow[v] = o;
        }
      }
    } else {
      int vb = bx * 2 + half;
      if (vb < 464) {
        int b2 = vb - 64, nb = b2 & 7, kb = b2 >> 3;  // kb 0..49
        int l = vt & 63, wv = vt >> 6;
        int mrow = wv * 16 + (l & 15);
        int qk = (l >> 4) * 8;
        const bf16* ap = a.Ebf + (size_t)mrow * 32000 + kb * 640 + qk;
        int ncol = nb * 64 + (l & 15);
        const bf16* bp[4];
#pragma unroll
        for (int jj = 0; jj < 4; ++jj)
          bp[jj] = a.EyT + (size_t)(ncol + 16 * jj) * 32000 + kb * 640 + qk;
        f32x4 acc[4];
#pragma unroll
        for (int jj = 0; jj < 4; ++jj) acc[jj] = {0.f, 0.f, 0.f, 0.f};
#pragma unroll 4
        for (int s = 0; s < 20; ++s) {
          bf16x8 av = *(const bf16x8*)ap; ap += 32;
#pragma unroll
          for (int jj = 0; jj < 4; ++jj) {
            bf16x8 bv = *(const bf16x8*)bp[jj]; bp[jj] += 32;
            acc[jj] = MFMA16(av, bv, acc[jj]);
          }
        }
        int row = wv * 16 + (l >> 4) * 4;
        int col = nb * 64 + (l & 15);
#pragma unroll
        for (int jj = 0; jj < 4; ++jj)
#pragma unroll
          for (int i = 0; i < 4; ++i)
            atomicAdd(&a.t1f[(size_t)(row + i) * 512 + col + jj * 16], acc[jj][i]);
      }
    }
    grid.sync();

    // ======== Phase B: GRU (64 blocks, 2-way K-split) ========
    if (bx < 64) {
      int h0 = bx * 16;
      int rw = wave & 3, kg = wave >> 2;  // kg 0..1
      int m = rw * 16 + (lane & 15);
      int qk = (lane >> 4) * 8;
      int hl = lane & 15;
      f32x4 gi[3], gh[3];
#pragma unroll
      for (int g = 0; g < 3; ++g) { gi[g] = {0.f, 0.f, 0.f, 0.f}; gh[g] = {0.f, 0.f, 0.f, 0.f}; }
      {  // gi = ctx @ W_ih^T (K=512 -> 8 ksteps per kg)
        const bf16* ah = a.ctx_hi + (size_t)m * 512 + kg * 256 + qk;
        const bf16* al = a.ctx_lo + (size_t)m * 512 + kg * 256 + qk;
        const bf16* bh[3]; const bf16* bl[3];
#pragma unroll
        for (int g = 0; g < 3; ++g) {
          size_t r = (size_t)(g * 1024 + h0 + hl) * 512 + kg * 256 + qk;
          bh[g] = a.Wih_hi + r; bl[g] = a.Wih_lo + r;
        }
#pragma unroll 4
        for (int s = 0; s < 8; ++s) {
          bf16x8 Ah = *(const bf16x8*)ah; ah += 32;
          bf16x8 Al = *(const bf16x8*)al; al += 32;
#pragma unroll
          for (int g = 0; g < 3; ++g) {
            bf16x8 Bh = *(const bf16x8*)bh[g]; bh[g] += 32;
            bf16x8 Bl = *(const bf16x8*)bl[g]; bl[g] += 32;
            gi[g] = MFMA16(Ah, Bh, gi[g]);
            gi[g] = MFMA16(Ah, Bl, gi[g]);
            gi[g] = MFMA16(Al, Bh, gi[g]);
          }
        }
      }
      {  // gh = s @ W_hh^T (K=1024 -> 16 ksteps per kg)
        const bf16* ah = shc + (size_t)m * 1024 + kg * 512 + qk;
        const bf16* al = slc + (size_t)m * 1024 + kg * 512 + qk;
        const bf16* bh[3]; const bf16* bl[3];
#pragma unroll
        for (int g = 0; g < 3; ++g) {
          size_t r = (size_t)(g * 1024 + h0 + hl) * 1024 + kg * 512 + qk;
          bh[g] = a.Whh_hi + r; bl[g] = a.Whh_lo + r;
        }
#pragma unroll 4
        for (int s = 0; s < 16; ++s) {
          bf16x8 Ah = *(const bf16x8*)ah; ah += 32;
          bf16x8 Al = *(const bf16x8*)al; al += 32;
#pragma unroll
          for (int g = 0; g < 3; ++g) {
            bf16x8 Bh = *(const bf16x8*)bh[g]; bh[g] += 32;
            bf16x8 Bl = *(const bf16x8*)bl[g]; bl[g] += 32;
            gh[g] = MFMA16(Ah, Bh, gh[g]);
            gh[g] = MFMA16(Ah, Bl, gh[g]);
            gh[g] = MFMA16(Al, Bh, gh[g]);
          }
        }
      }
      float* red = smem;  // [4][64] x 25 floats (padded)
      if (kg == 1) {
        float* d = red + (rw * 64 + lane) * 25;
#pragma unroll
        for (int g = 0; g < 3; ++g)
#pragma unroll
          for (int i = 0; i < 4; ++i) { d[g * 4 + i] = gi[g][i]; d[12 + g * 4 + i] = gh[g][i]; }
      }
      __syncthreads();
      if (kg == 0) {
        const float* d = red + (rw * 64 + lane) * 25;
#pragma unroll
        for (int g = 0; g < 3; ++g)
#pragma unroll
          for (int i = 0; i < 4; ++i) { gi[g][i] += d[g * 4 + i]; gh[g][i] += d[12 + g * 4 + i]; }
        int hg = h0 + hl;
        float bir = a.b_ih[hg], biz = a.b_ih[1024 + hg], bin = a.b_ih[2048 + hg];
        float bhr = a.b_hh[hg], bhz = a.b_hh[1024 + hg], bhn = a.b_hh[2048 + hg];
        int brow0 = rw * 16 + (lane >> 4) * 4;
#pragma unroll
        for (int i = 0; i < 4; ++i) {
          int b = brow0 + i;
          float r = fast_sigmoid(gi[0][i] + bir + gh[0][i] + bhr);
          float z = fast_sigmoid(gi[1][i] + biz + gh[1][i] + bhz);
          float n = fast_tanh(gi[2][i] + bin + r * (gh[2][i] + bhn));
          float so = s_cur[(size_t)b * 1024 + hg];
          float sn = (1.f - z) * n + z * so;
          s_nxt[(size_t)b * 1024 + hg] = sn;
          bf16 hh = (bf16)sn;
          shn[(size_t)b * 1024 + hg] = hh;
          sln[(size_t)b * 1024 + hg] = (bf16)(sn - (float)hh);
        }
      }
    }
    grid.sync();

    // ======== Phase C: deepout+maxout | Ws = s_new @ W ========
    if (bx < 64) {
      int n0 = bx * 16;
      int rw = wave & 3, kg = wave >> 2;
      int m = rw * 16 + (lane & 15);
      int nr = n0 + (lane & 15);
      int qk = (lane >> 4) * 8;
      f32x4 acc = {0.f, 0.f, 0.f, 0.f};
      if (kg == 0) {  // s_new @ U_o (K=1024, 32 ksteps)
        const bf16* ah = shn + (size_t)m * 1024 + qk;
        const bf16* al = sln + (size_t)m * 1024 + qk;
        const bf16* bh = a.UoT_hi + (size_t)nr * 1024 + qk;
        const bf16* bl = a.UoT_lo + (size_t)nr * 1024 + qk;
#pragma unroll 4
        for (int s = 0; s < 32; ++s) {
          bf16x8 Ah = *(const bf16x8*)ah; ah += 32;
          bf16x8 Al = *(const bf16x8*)al; al += 32;
          bf16x8 Bh = *(const bf16x8*)bh; bh += 32;
          bf16x8 Bl = *(const bf16x8*)bl; bl += 32;
          acc = MFMA16(Ah, Bh, acc); acc = MFMA16(Ah, Bl, acc); acc = MFMA16(Al, Bh, acc);
        }
      } else {  // (t1*invZ) @ V_o (16 ksteps) + ctx @ C_o (16 ksteps)
        float iz = a.invZ[m];
        const float* ap = a.t1f + (size_t)m * 512 + qk;
        const bf16* bh = a.VoT_hi + (size_t)nr * 512 + qk;
        const bf16* bl = a.VoT_lo + (size_t)nr * 512 + qk;
#pragma unroll 4
        for (int s = 0; s < 16; ++s) {
          f32x4 f0 = *(const f32x4*)ap;
          f32x4 f1 = *(const f32x4*)(ap + 4);
          ap += 32;
          bf16x8 Ah, Al;
#pragma unroll
          for (int i = 0; i < 4; ++i) {
            float x = f0[i] * iz; bf16 hv = (bf16)x; Ah[i] = hv; Al[i] = (bf16)(x - (float)hv);
            x = f1[i] * iz; hv = (bf16)x; Ah[4 + i] = hv; Al[4 + i] = (bf16)(x - (float)hv);
          }
          bf16x8 Bh = *(const bf16x8*)bh; bh += 32;
          bf16x8 Bl = *(const bf16x8*)bl; bl += 32;
          acc = MFMA16(Ah, Bh, acc); acc = MFMA16(Ah, Bl, acc); acc = MFMA16(Al, Bh, acc);
        }
        const bf16* ah = a.ctx_hi + (size_t)m * 512 + qk;
        const bf16* al2 = a.ctx_lo + (size_t)m * 512 + qk;
        const bf16* bh2 = a.CoT_hi + (size_t)nr * 512 + qk;
        const bf16* bl2 = a.CoT_lo + (size_t)nr * 512 + qk;
#pragma unroll 4
        for (int s = 0; s < 16; ++s) {
          bf16x8 Ah = *(const bf16x8*)ah; ah += 32;
          bf16x8 Al = *(const bf16x8*)al2; al2 += 32;
          bf16x8 Bh = *(const bf16x8*)bh2; bh2 += 32;
          bf16x8 Bl = *(const bf16x8*)bl2; bl2 += 32;
          acc = MFMA16(Ah, Bh, acc); acc = MFMA16(Ah, Bl, acc); acc = MFMA16(Al, Bh, acc);
        }
      }
      f32x4* redD = (f32x4*)smem;
      if (kg == 1) redD[rw * 64 + lane] = acc;
      __syncthreads();
      if (kg == 0) {
        f32x4 o = redD[rw * 64 + lane];
        acc = acc + o;
        int col = lane & 15;
        int row0 = rw * 16 + (lane >> 4) * 4;
#pragma unroll
        for (int i = 0; i < 4; ++i) {
          float vme = acc[i];
          float vot = __shfl_xor(vme, 1);
          float mx = fmaxf(vme, vot);
          if (!(col & 1)) {
            int d = (n0 + col) >> 1;
            a.tm_bf[(size_t)(row0 + i) * 512 + d] = (bf16)mx;
          }
        }
      }
    } else if (bx < 72) {
      int nb = bx - 64;
      int rw = wave & 3, kg = wave >> 2;
      int m = rw * 16 + (lane & 15);
      int ncol = nb * 64 + (lane & 15);
      int qk = (lane >> 4) * 8;
      const bf16* ah = shn + (size_t)m * 1024 + kg * 512 + qk;
      const bf16* al = sln + (size_t)m * 1024 + kg * 512 + qk;
      const bf16* bh[4]; const bf16* bl[4];
#pragma unroll
      for (int jj = 0; jj < 4; ++jj) {
        size_t r = (size_t)(ncol + 16 * jj) * 1024 + kg * 512 + qk;
        bh[jj] = a.WT_hi + r; bl[jj] = a.WT_lo + r;
      }
      f32x4 acc[4];
#pragma unroll
      for (int jj = 0; jj < 4; ++jj) acc[jj] = {0.f, 0.f, 0.f, 0.f};
#pragma unroll 2
      for (int s = 0; s < 16; ++s) {
        bf16x8 Ah = *(const bf16x8*)ah; ah += 32;
        bf16x8 Al = *(const bf16x8*)al; al += 32;
#pragma unroll
        for (int jj = 0; jj < 4; ++jj) {
          bf16x8 Bh = *(const bf16x8*)bh[jj]; bh[jj] += 32;
          bf16x8 Bl = *(const bf16x8*)bl[jj]; bl[jj] += 32;
          acc[jj] = MFMA16(Ah, Bh, acc[jj]);
          acc[jj] = MFMA16(Ah, Bl, acc[jj]);
          acc[jj] = MFMA16(Al, Bh, acc[jj]);
        }
      }
      f32x4* redW = (f32x4*)smem;
      if (kg == 1) {
#pragma unroll
        for (int jj = 0; jj < 4; ++jj) redW[(rw * 64 + lane) * 5 + jj] = acc[jj];
      }
      __syncthreads();
      if (kg == 0) {
#pragma unroll
        for (int jj = 0; jj < 4; ++jj) {
          f32x4 o = redW[(rw * 64 + lane) * 5 + jj];
          acc[jj] = acc[jj] + o;
        }
        int row = rw * 16 + (lane >> 4) * 4;
#pragma unroll
        for (int jj = 0; jj < 4; ++jj)
#pragma unroll
          for (int i = 0; i < 4; ++i)
            a.Ws[(size_t)(row + i) * 512 + nb * 64 + (lane & 15) + jj * 16] = acc[jj][i];
      }
    }
    grid.sync();

    // ======== Phase D: E = exp(tm @ W_o), Zpart, zero t1f ========
    {
      int vb = bx * 2 + half;
      if (vb < 500) {
        if (vb < 64) {
          a.t1f[vb * 512 + vt] = 0.f;
          a.t1f[vb * 512 + 256 + vt] = 0.f;
        }
        int l = vt & 63, wv = vt >> 6;
        int mrow = wv * 16 + (l & 15);
        int qk = (l >> 4) * 8;
        const bf16* ap = a.tm_bf + (size_t)mrow * 512 + qk;
        int ncol = vb * 64 + (l & 15);
        const bf16* bp[4];
#pragma unroll
        for (int jj = 0; jj < 4; ++jj) bp[jj] = a.WoT + (size_t)(ncol + 16 * jj) * 512 + qk;
        f32x4 acc[4];
#pragma unroll
        for (int jj = 0; jj < 4; ++jj) acc[jj] = {0.f, 0.f, 0.f, 0.f};
#pragma unroll 4
        for (int s = 0; s < 16; ++s) {
          bf16x8 av = *(const bf16x8*)ap; ap += 32;
#pragma unroll
          for (int jj = 0; jj < 4; ++jj) {
            bf16x8 bv = *(const bf16x8*)bp[jj]; bp[jj] += 32;
            acc[jj] = MFMA16(av, bv, acc[jj]);
          }
        }
        int row0 = wv * 16 + (l >> 4) * 4;
        int col = vb * 64 + (l & 15);
        float rs[4] = {0.f, 0.f, 0.f, 0.f};
#pragma unroll
        for (int jj = 0; jj < 4; ++jj)
#pragma unroll
          for (int i = 0; i < 4; ++i) {
            float e = __expf(acc[jj][i]);
            size_t idx = (size_t)(row0 + i) * 32000 + col + jj * 16;
            a.Ef[idx] = e;
            a.Ebf[idx] = (bf16)e;
            rs[i] += e;
          }
#pragma unroll
        for (int i = 0; i < 4; ++i) {
          float s = rs[i];
          s += __shfl_xor(s, 1); s += __shfl_xor(s, 2); s += __shfl_xor(s, 4); s += __shfl_xor(s, 8);
          rs[i] = s;
        }
        if ((l & 15) == 0) {
#pragma unroll
          for (int i = 0; i < 4; ++i) a.Zpart[vb * 64 + row0 + i] = rs[i];
        }
      }
    }
    grid.sync();
  }

  // ======== final: out[63] = E * invZ ========
  if (bx < 32) {
    int b = bx * 2 + half;
    float part = 0.f;
    for (int nb = vt; nb < 500; nb += 256) part += a.Zpart[nb * 64 + b];
#pragma unroll
    for (int off = 32; off; off >>= 1) part += __shfl_xor(part, off);
    float* w4 = smem;
    if ((vt & 63) == 0) w4[half * 4 + (vt >> 6)] = part;
    __syncthreads();
    float iz = 1.f / (w4[half * 4] + w4[half * 4 + 1] + w4[half * 4 + 2] + w4[half * 4 + 3]);
    const f32x4* er = (const f32x4*)(a.Ef + (size_t)b * 32000);
    f32x4* orow = (f32x4*)(a.out + ((size_t)63 * 64 + b) * 32000);
    for (int v = vt; v < 8000; v += 256) {
      f32x4 e = er[v];
      f32x4 o = {e[0] * iz, e[1] * iz, e[2] * iz, e[3] * iz};
      orow[v] = o;
    }
  }
}

// ---------------- host ----------------

extern "C" void kernel_launch(void* const* d_in, const int* in_sizes, int n_in,
                              void* d_out, int out_size, void* d_ws, size_t ws_size,
                              hipStream_t stream) {
  const float* input_seq = (const float*)d_in[0];
  const float* Ey_t = (const float*)d_in[1];
  const float* W = (const float*)d_in[2];
  const float* U = (const float*)d_in[3];
  const float* attnb = (const float*)d_in[4];
  const float* vvec = (const float*)d_in[5];
  const float* W_ih = (const float*)d_in[6];
  const float* W_hh = (const float*)d_in[7];
  const float* b_ih = (const float*)d_in[8];
  const float* b_hh = (const float*)d_in[9];
  const float* U_o = (const float*)d_in[10];
  const float* V_o = (const float*)d_in[11];
  const float* C_o = (const float*)d_in[12];
  const float* W_o = (const float*)d_in[13];
  float* out = (float*)d_out;

  char* p = (char*)d_ws;
  auto alloc = [&](size_t bytes) -> char* {
    char* r = p;
    p += (bytes + 255) & ~(size_t)255;
    return r;
  };
  // --- zero block (memset once per launch) ---
  float* sbuf0 = (float*)alloc(64 * 1024 * 4);
  bf16* shi0 = (bf16*)alloc(64 * 1024 * 2);
  bf16* slo0 = (bf16*)alloc(64 * 1024 * 2);
  float* Ws = (float*)alloc(64 * 512 * 4);
  float* t1f = (float*)alloc(64 * 512 * 4);
  bf16* y_bf = (bf16*)alloc((size_t)64 * 32000 * 2);
  size_t zeroBytes = (size_t)(p - (char*)d_ws);
  // --- rest ---
  float* sbuf1 = (float*)alloc(64 * 1024 * 4);
  bf16* shi1 = (bf16*)alloc(64 * 1024 * 2);
  bf16* slo1 = (bf16*)alloc(64 * 1024 * 2);
  bf16* ctx_hi = (bf16*)alloc(64 * 512 * 2);
  bf16* ctx_lo = (bf16*)alloc(64 * 512 * 2);
  bf16* tm_bf = (bf16*)alloc(64 * 512 * 2);
  float* Ef = (float*)alloc((size_t)64 * 32000 * 4);
  float* Zpart = (float*)alloc((size_t)500 * 64 * 4);
  float* invZ = (float*)alloc(64 * 4);
  float* U_h = (float*)alloc((size_t)4096 * 512 * 4);
  bf16* in_hi = (bf16*)alloc((size_t)4096 * 512 * 2);
  bf16* in_lo = (bf16*)alloc((size_t)4096 * 512 * 2);
  bf16* UT_hi = (bf16*)alloc(512 * 512 * 2);
  bf16* UT_lo = (bf16*)alloc(512 * 512 * 2);
  bf16* EyT = (bf16*)alloc((size_t)512 * 32000 * 2);
  bf16* WoT = (bf16*)alloc((size_t)32000 * 512 * 2);
  bf16* UoT_hi = (bf16*)alloc((size_t)1024 * 1024 * 2);
  bf16* UoT_lo = (bf16*)alloc((size_t)1024 * 1024 * 2);
  bf16* VoT_hi = (bf16*)alloc((size_t)1024 * 512 * 2);
  bf16* VoT_lo = (bf16*)alloc((size_t)1024 * 512 * 2);
  bf16* CoT_hi = (bf16*)alloc((size_t)1024 * 512 * 2);
  bf16* CoT_lo = (bf16*)alloc((size_t)1024 * 512 * 2);
  bf16* WT_hi = (bf16*)alloc((size_t)512 * 1024 * 2);
  bf16* WT_lo = (bf16*)alloc((size_t)512 * 1024 * 2);
  bf16* Wih_hi = (bf16*)alloc((size_t)3072 * 512 * 2);
  bf16* Wih_lo = (bf16*)alloc((size_t)3072 * 512 * 2);
  bf16* Whh_hi = (bf16*)alloc((size_t)3072 * 1024 * 2);
  bf16* Whh_lo = (bf16*)alloc((size_t)3072 * 1024 * 2);

  hipMemsetAsync(d_ws, 0, zeroBytes, stream);

  // setup: casts / transposes / U_h
  cast_split_kernel<<<(4096 * 512) / 256, 256, 0, stream>>>(input_seq, in_hi, in_lo, 4096 * 512);
  cast_split_kernel<<<(3072 * 512) / 256, 256, 0, stream>>>(W_ih, Wih_hi, Wih_lo, 3072 * 512);
  cast_split_kernel<<<(3072 * 1024) / 256, 256, 0, stream>>>(W_hh, Whh_hi, Whh_lo, 3072 * 1024);
  tc_kernel<<<dim3(512 / 32, 512 / 32), 256, 0, stream>>>(U, UT_hi, UT_lo, 512, 512);
  tc_kernel<<<dim3(512 / 32, 32000 / 32), 256, 0, stream>>>(Ey_t, EyT, nullptr, 32000, 512);
  tc_kernel<<<dim3(32000 / 32, 512 / 32), 256, 0, stream>>>(W_o, WoT, nullptr, 512, 32000);
  tc_kernel<<<dim3(1024 / 32, 1024 / 32), 256, 0, stream>>>(U_o, UoT_hi, UoT_lo, 1024, 1024);
  tc_kernel<<<dim3(1024 / 32, 512 / 32), 256, 0, stream>>>(V_o, VoT_hi, VoT_lo, 512, 1024);
  tc_kernel<<<dim3(1024 / 32, 512 / 32), 256, 0, stream>>>(C_o, CoT_hi, CoT_lo, 512, 1024);
  tc_kernel<<<dim3(512 / 32, 1024 / 32), 256, 0, stream>>>(W, WT_hi, WT_lo, 1024, 512);
  gemm_split_kernel<<<64 * 8, 256, 0, stream>>>(in_hi, in_lo, 512, UT_hi, UT_lo, 512,
                                                U_h, 512, 8, 16);

  MegaArgs ma;
  ma.U_h = U_h; ma.attnb = attnb; ma.vvec = vvec; ma.inseq = input_seq;
  ma.Ws = Ws;
  ma.ctx_hi = ctx_hi; ma.ctx_lo = ctx_lo;
  ma.Ebf = y_bf; ma.EyT = EyT; ma.t1f = t1f;
  ma.Ef = Ef; ma.Zpart = Zpart; ma.invZ = invZ; ma.out = out;
  ma.sbuf0 = sbuf0; ma.sbuf1 = sbuf1;
  ma.shi0 = shi0; ma.slo0 = slo0; ma.shi1 = shi1; ma.slo1 = slo1;
  ma.Wih_hi = Wih_hi; ma.Wih_lo = Wih_lo; ma.Whh_hi = Whh_hi; ma.Whh_lo = Whh_lo;
  ma.b_ih = b_ih; ma.b_hh = b_hh;
  ma.UoT_hi = UoT_hi; ma.UoT_lo = UoT_lo; ma.VoT_hi = VoT_hi; ma.VoT_lo = VoT_lo;
  ma.CoT_hi = CoT_hi; ma.CoT_lo = CoT_lo; ma.WT_hi = WT_hi; ma.WT_lo = WT_lo;
  ma.WoT = WoT; ma.tm_bf = tm_bf;

  void* kargs[] = {&ma};
  hipLaunchCooperativeKernel((const void*)mega_kernel, dim3(256), dim3(512), kargs, 0, stream);

  (void)in_sizes; (void)n_in; (void)out_size; (void)ws_size;
}